// Round 9
// baseline (302.595 us; speedup 1.0000x reference)
//
#include <hip/hip_runtime.h>

#define D 128
#define BUNROLL 8
#define RPB 128                 // rows per bucket
#define CAP 2560                // max edges sorted in LDS per bucket (avg ~1920, Poisson sigma~44)
#define MAXK 2048               // max buckets (LDS histogram size)
#define CHUNK4 8192             // edges per block in hist4/scatter4 (identical mapping!)
#define STILE 1024              // scan tile

// ---------------- relation transform (both matrices in one launch) ----------------
__global__ void transform2_kernel(const float* __restrict__ Rin, const float* __restrict__ Win,
                                  const float* __restrict__ Rout, const float* __restrict__ Wout,
                                  float* __restrict__ T_all, int nrel) {
    __shared__ float row[D];
    int b = blockIdx.x;
    bool second = (b >= nrel);
    const float* R = second ? Rout : Rin;
    const float* W = second ? Wout : Win;
    int r = second ? b - nrel : b;
    int t = threadIdx.x;
    row[t] = R[r * D + t];
    __syncthreads();
    float acc = 0.f;
#pragma unroll 8
    for (int k = 0; k < D; ++k) acc += row[k] * W[k * D + t];
    T_all[(size_t)b * D + t] = acc;
}

// ---------------- pass 1: per-block LDS bucket histogram (NO global atomics) ----------------
// cnt[bucket * NB + blk] = #edges of this block in bucket
__global__ __launch_bounds__(512) void hist4_kernel(
        const int* __restrict__ rows, int E2,
        unsigned* __restrict__ cnt, int NB, int K) {
    __shared__ unsigned h[MAXK];
    int tid = threadIdx.x, blk = blockIdx.x;
    for (int i = tid; i < K; i += 512) h[i] = 0;
    __syncthreads();
    long s = (long)blk * CHUNK4;
    long e = s + CHUNK4; if (e > E2) e = E2;
    for (long i = s + tid; i < e; i += 512)
        atomicAdd(&h[((unsigned)rows[i]) >> 7], 1u);
    __syncthreads();
    for (int i = tid; i < K; i += 512)
        cnt[(size_t)i * NB + blk] = h[i];
}

// ---------------- device-wide scan over n=NB*K counters (3 kernels, in-place alias ok) ----
__global__ __launch_bounds__(256) void tile_sum_u32(const unsigned int* __restrict__ cnt,
                                                    unsigned int* __restrict__ tsum, int n) {
    int tid = threadIdx.x;
    int i0 = blockIdx.x * STILE + tid * 4;
    unsigned int s = 0;
#pragma unroll
    for (int k = 0; k < 4; ++k) {
        int i = i0 + k;
        if (i < n) s += cnt[i];
    }
    __shared__ unsigned int ls[256];
    ls[tid] = s;
    __syncthreads();
    for (int off = 128; off >= 1; off >>= 1) {
        if (tid < off) ls[tid] += ls[tid + off];
        __syncthreads();
    }
    if (tid == 0) tsum[blockIdx.x] = ls[0];
}

__global__ void scan_tiles_kernel(const unsigned int* __restrict__ tile_sums,
                                  unsigned int* __restrict__ tile_off,
                                  unsigned int* __restrict__ base, int ntiles, int n) {
    int t = threadIdx.x; // blockDim = 1024
    __shared__ unsigned int ls[1024];
    unsigned int v = (t < ntiles) ? tile_sums[t] : 0u;
    ls[t] = v;
    __syncthreads();
    for (int off = 1; off < 1024; off <<= 1) {
        unsigned int add = (t >= off) ? ls[t - off] : 0u;
        __syncthreads();
        ls[t] += add;
        __syncthreads();
    }
    if (t < ntiles) tile_off[t] = ls[t] - v; // exclusive
    if (t == 1023) base[n] = ls[1023];       // grand total
}

// in-place safe when base==cnt: each element read before written by its own thread
__global__ __launch_bounds__(256) void base_write_u32(const unsigned int* __restrict__ cnt,
                                                      const unsigned int* __restrict__ tile_off,
                                                      unsigned int* __restrict__ base, int n) {
    int tid = threadIdx.x;
    int i0 = blockIdx.x * STILE + tid * 4;
    unsigned int c[4];
#pragma unroll
    for (int k = 0; k < 4; ++k) {
        int i = i0 + k;
        c[k] = (i < n) ? cnt[i] : 0u;
    }
    unsigned int s = c[0] + c[1] + c[2] + c[3];
    __shared__ unsigned int ls[256];
    ls[tid] = s;
    __syncthreads();
    for (int off = 1; off < 256; off <<= 1) {
        unsigned int add = (tid >= off) ? ls[tid - off] : 0u;
        __syncthreads();
        ls[tid] += add;
        __syncthreads();
    }
    unsigned int run = (tid > 0 ? ls[tid - 1] : 0u) + tile_off[blockIdx.x];
#pragma unroll
    for (int k = 0; k < 4; ++k) {
        int i = i0 + k;
        if (i < n) base[i] = run;
        run += c[k];
    }
}

// ---------------- pass 2: scatter with LDS ranks (NO global atomics) ----------------
// payload = (col, (row&127)<<10 | type)   -- coeff deferred to accum
__global__ __launch_bounds__(512) void scatter4_kernel(
        const int* __restrict__ rows, const int* __restrict__ cols,
        const int* __restrict__ etype, const unsigned* __restrict__ base,
        uint2* __restrict__ payload, int E, int E2, int nrel, int NB, int K) {
    __shared__ unsigned cur[MAXK];
    int tid = threadIdx.x, blk = blockIdx.x;
    for (int i = tid; i < K; i += 512) cur[i] = base[(size_t)i * NB + blk];
    __syncthreads();
    long s = (long)blk * CHUNK4;
    long e = s + CHUNK4; if (e > E2) e = E2;
    for (long i = s + tid; i < e; i += 512) {
        unsigned r = (unsigned)rows[i];
        unsigned c = (unsigned)cols[i];
        unsigned t = (unsigned)etype[i];
        unsigned ty = t + ((i < E) ? 0u : (unsigned)nrel);
        unsigned pos = atomicAdd(&cur[r >> 7], 1u);   // LDS atomic
        payload[pos] = make_uint2(c, ((r & 127u) << 10) | ty);
    }
}

// ---------------- degrees from sorted payload (NO global atomics) ----------------
// dinvAll[0..nent) = deg_in^-1/2 ; dinvAll[nent..2nent) = deg_out^-1/2
__global__ __launch_bounds__(512) void degsort_kernel(
        const unsigned* __restrict__ base, const uint2* __restrict__ payload,
        float* __restrict__ dinvAll, int nent, int nrel, int NB, int K) {
    __shared__ unsigned h2[RPB * 2];
    int tid = threadIdx.x, b = blockIdx.x;
    for (int i = tid; i < RPB * 2; i += 512) h2[i] = 0;
    __syncthreads();
    size_t NBK = (size_t)NB * K;
    unsigned s = base[(size_t)b * NB];
    unsigned e = (b + 1 < K) ? base[(size_t)(b + 1) * NB] : base[NBK];
    for (unsigned i = s + tid; i < e; i += 512) {
        unsigned y = payload[i].y;
        unsigned lr = (y >> 10) & 127u;
        unsigned fo = ((y & 1023u) >= (unsigned)nrel) ? 1u : 0u;
        atomicAdd(&h2[lr * 2 + fo], 1u);
    }
    __syncthreads();
    if (tid < RPB) {
        int row = (b << 7) + tid;
        if (row < nent) {
            unsigned a = h2[tid * 2], o = h2[tid * 2 + 1];
            dinvAll[row]        = a ? rsqrtf((float)a) : 0.f;
            dinvAll[nent + row] = o ? rsqrtf((float)o) : 0.f;
        }
    }
}

// ---------------- per-bucket LDS sort + register accumulate + fused BN stats ----------------
__global__ __launch_bounds__(512) void accum4_kernel(
        const unsigned* __restrict__ base, const uint2* __restrict__ payload,
        const float* __restrict__ T_all, const float* __restrict__ dinvAll,
        float* __restrict__ out, float* __restrict__ sums, float* __restrict__ sumsq,
        int nent, int nrel, int NB, int K) {
    __shared__ uint2 sp[CAP];              // 20 KB
    __shared__ unsigned hist[RPB];
    __shared__ unsigned hcur[RPB];
    __shared__ float ls[D], lq[D];
    int tid = threadIdx.x;
    int b = blockIdx.x;
    size_t NBK = (size_t)NB * K;
    unsigned start = base[(size_t)b * NB];
    unsigned end   = (b + 1 < K) ? base[(size_t)(b + 1) * NB] : base[NBK];
    int n = (int)(end - start);
    int nin = n < CAP ? n : CAP;

    if (tid < RPB) { hist[tid] = 0; ls[tid] = 0.f; lq[tid] = 0.f; }
    __syncthreads();
    for (int i = tid; i < nin; i += 512)
        atomicAdd(&hist[(payload[start + i].y >> 10) & 127u], 1u);
    __syncthreads();
    for (int off = 1; off < RPB; off <<= 1) {
        unsigned v = 0;
        if (tid < RPB && tid >= off) v = hist[tid - off];
        __syncthreads();
        if (tid < RPB) hist[tid] += v;
        __syncthreads();
    }
    if (tid < RPB) hcur[tid] = tid ? hist[tid - 1] : 0u;
    __syncthreads();
    for (int i = tid; i < nin; i += 512) {
        uint2 p = payload[start + i];
        unsigned pos = atomicAdd(&hcur[(p.y >> 10) & 127u], 1u);
        sp[pos] = p;
    }
    __syncthreads();

    const float4* T4 = (const float4*)T_all;
    float4* out4 = (float4*)out;
    int hw = tid >> 5, l32 = tid & 31;
    int row0 = b << 7;
    unsigned unrel = (unsigned)nrel;
    float4 s4 = make_float4(0.f, 0.f, 0.f, 0.f);
    float4 q4 = make_float4(0.f, 0.f, 0.f, 0.f);
    for (int rr = 0; rr < 8; ++rr) {
        int r = (hw << 3) + rr;
        int row = row0 + r;
        float da_in = 0.f, da_out = 0.f;
        if (row < nent) { da_in = dinvAll[row]; da_out = dinvAll[nent + row]; }
        unsigned s0 = r ? hist[r - 1] : 0u;
        unsigned s1 = hist[r];
        float4 a = make_float4(0.f, 0.f, 0.f, 0.f);
        unsigned i = s0;
        for (; i + 4 <= s1; i += 4) {      // 4-deep independent chains
            uint2 p0 = sp[i], p1 = sp[i + 1], p2 = sp[i + 2], p3 = sp[i + 3];
            unsigned ty0 = p0.y & 1023u, ty1 = p1.y & 1023u;
            unsigned ty2 = p2.y & 1023u, ty3 = p3.y & 1023u;
            bool f0 = ty0 < unrel, f1 = ty1 < unrel, f2 = ty2 < unrel, f3 = ty3 < unrel;
            float dc0 = dinvAll[(f0 ? 0 : nent) + p0.x];
            float dc1 = dinvAll[(f1 ? 0 : nent) + p1.x];
            float dc2 = dinvAll[(f2 ? 0 : nent) + p2.x];
            float dc3 = dinvAll[(f3 ? 0 : nent) + p3.x];
            float4 t0 = T4[(size_t)ty0 * 32 + l32];
            float4 t1 = T4[(size_t)ty1 * 32 + l32];
            float4 t2 = T4[(size_t)ty2 * 32 + l32];
            float4 t3 = T4[(size_t)ty3 * 32 + l32];
            float c0 = 0.5f * (f0 ? da_in : da_out) * dc0;
            float c1 = 0.5f * (f1 ? da_in : da_out) * dc1;
            float c2 = 0.5f * (f2 ? da_in : da_out) * dc2;
            float c3 = 0.5f * (f3 ? da_in : da_out) * dc3;
            a.x += c0 * t0.x; a.y += c0 * t0.y; a.z += c0 * t0.z; a.w += c0 * t0.w;
            a.x += c1 * t1.x; a.y += c1 * t1.y; a.z += c1 * t1.z; a.w += c1 * t1.w;
            a.x += c2 * t2.x; a.y += c2 * t2.y; a.z += c2 * t2.z; a.w += c2 * t2.w;
            a.x += c3 * t3.x; a.y += c3 * t3.y; a.z += c3 * t3.z; a.w += c3 * t3.w;
        }
        for (; i < s1; ++i) {
            uint2 p = sp[i];
            unsigned ty = p.y & 1023u;
            bool f = ty < unrel;
            float c = 0.5f * (f ? da_in : da_out) * dinvAll[(f ? 0 : nent) + p.x];
            float4 t = T4[(size_t)ty * 32 + l32];
            a.x += c * t.x; a.y += c * t.y; a.z += c * t.z; a.w += c * t.w;
        }
        // overflow tail (n > CAP): scan remaining global payload (correctness fallback)
        for (unsigned j = start + (unsigned)nin; j < end; ++j) {
            uint2 p = payload[j];
            if (((p.y >> 10) & 127u) == (unsigned)r) {
                unsigned ty = p.y & 1023u;
                bool f = ty < unrel;
                float c = 0.5f * (f ? da_in : da_out) * dinvAll[(f ? 0 : nent) + p.x];
                float4 t = T4[(size_t)ty * 32 + l32];
                a.x += c * t.x; a.y += c * t.y; a.z += c * t.z; a.w += c * t.w;
            }
        }
        if (row < nent) {
            out4[(size_t)row * 32 + l32] = a;
            s4.x += a.x; s4.y += a.y; s4.z += a.z; s4.w += a.w;
            q4.x += a.x * a.x; q4.y += a.y * a.y; q4.z += a.z * a.z; q4.w += a.w * a.w;
        }
    }
    atomicAdd(&ls[4 * l32 + 0], s4.x); atomicAdd(&ls[4 * l32 + 1], s4.y);
    atomicAdd(&ls[4 * l32 + 2], s4.z); atomicAdd(&ls[4 * l32 + 3], s4.w);
    atomicAdd(&lq[4 * l32 + 0], q4.x); atomicAdd(&lq[4 * l32 + 1], q4.y);
    atomicAdd(&lq[4 * l32 + 2], q4.z); atomicAdd(&lq[4 * l32 + 3], q4.w);
    __syncthreads();
    if (tid < D) {
        atomicAdd(&sums[tid], ls[tid]);
        atomicAdd(&sumsq[tid], lq[tid]);
    }
}

// ---------------- fallback (atomic) path kernels ----------------
__global__ __launch_bounds__(256) void degree_kernel(const int* __restrict__ rows, int E,
                                                     float* __restrict__ deg_in,
                                                     float* __restrict__ deg_out) {
    int total = 2 * E;
    int tid = blockIdx.x * blockDim.x + threadIdx.x;
    int nth = gridDim.x * blockDim.x;
    for (long b = (long)tid * BUNROLL; b < total; b += (long)nth * BUNROLL) {
        for (int k = 0; k < BUNROLL && b + k < total; ++k) {
            int r = rows[b + k];
            float* deg = (b + k < E) ? deg_in : deg_out;
            atomicAdd(&deg[r], 1.0f);
        }
    }
}

__global__ void scatter_kernel(const int* __restrict__ rows, const int* __restrict__ cols,
                               const int* __restrict__ etype,
                               const float* __restrict__ deg_in, const float* __restrict__ deg_out,
                               const float* __restrict__ T_in, const float* __restrict__ T_out,
                               float* __restrict__ out, int E) {
    int wave = (blockIdx.x * blockDim.x + threadIdx.x) >> 6;
    int lane = threadIdx.x & 63;
    int nwaves = (gridDim.x * blockDim.x) >> 6;
    int total = 2 * E;
    for (int e = wave; e < total; e += nwaves) {
        bool first = (e < E);
        int row = rows[e];
        int col = cols[e];
        int t = etype[e];
        const float* deg = first ? deg_in : deg_out;
        const float* T = first ? T_in : T_out;
        float dr = deg[row];
        float dc = deg[col];
        float norm = (dr > 0.f ? rsqrtf(dr) : 0.f) * (dc > 0.f ? rsqrtf(dc) : 0.f);
        float c = 0.5f * norm;
        if (c != 0.f) {
            float v0 = c * T[t * D + lane];
            float v1 = c * T[t * D + 64 + lane];
            long b = (long)row * D;
            atomicAdd(&out[b + lane], v0);
            atomicAdd(&out[b + 64 + lane], v1);
        }
    }
}

__global__ void bn_stats_kernel(const float* __restrict__ h, int nent,
                                float* __restrict__ sums, float* __restrict__ sumsq) {
    int col = threadIdx.x;
    float s = 0.f, s2 = 0.f;
    for (int r = blockIdx.x; r < nent; r += gridDim.x) {
        float v = h[(long)r * D + col];
        s += v;
        s2 += v * v;
    }
    atomicAdd(&sums[col], s);
    atomicAdd(&sumsq[col], s2);
}

// ---------------- BN apply (both paths) ----------------
__global__ void bn_apply_kernel(float* __restrict__ h,
                                const float* __restrict__ sums, const float* __restrict__ sumsq,
                                const float* __restrict__ gamma, const float* __restrict__ beta,
                                int nent) {
    long total = ((long)nent * D) / 4;
    long stride = (long)gridDim.x * blockDim.x;
    float inv_n = 1.0f / (float)nent;
    float4* h4 = (float4*)h;
    for (long i = (long)blockIdx.x * blockDim.x + threadIdx.x; i < total; i += stride) {
        int c0 = (int)((i * 4) & (D - 1));
        float4 v = h4[i];
        float r[4] = {v.x, v.y, v.z, v.w};
#pragma unroll
        for (int j = 0; j < 4; ++j) {
            int col = c0 + j;
            float mean = sums[col] * inv_n;
            float var = sumsq[col] * inv_n - mean * mean;
            float istd = rsqrtf(var + 1e-5f);
            r[j] = tanhf((r[j] - mean) * istd * gamma[col] + beta[col]);
        }
        h4[i] = make_float4(r[0], r[1], r[2], r[3]);
    }
}

extern "C" void kernel_launch(void* const* d_in, const int* in_sizes, int n_in,
                              void* d_out, int out_size, void* d_ws, size_t ws_size,
                              hipStream_t stream) {
    const float* rel_embed     = (const float*)d_in[0];
    const float* rel_embed_in  = (const float*)d_in[1];
    const float* rel_embed_out = (const float*)d_in[2];
    const float* w_in          = (const float*)d_in[3];
    const float* w_out         = (const float*)d_in[4];
    const float* bn_gamma      = (const float*)d_in[5];
    const float* bn_beta       = (const float*)d_in[6];
    const int*   edge_index    = (const int*)d_in[7];
    const int*   edge_type     = (const int*)d_in[8];

    const int nrel = in_sizes[0] / D;               // 500
    const int E2   = in_sizes[8];                   // 3,000,000
    const int E    = E2 / 2;                        // 1,500,000
    const int nent = (out_size - in_sizes[0]) / D;  // 200,000
    const int K    = (nent + RPB - 1) / RPB;        // 1563 buckets
    const int NB   = (E2 + CHUNK4 - 1) / CHUNK4;    // 367 blocks
    const long NBK = (long)NB * K;                  // ~574K counters
    const int ntiles = (int)((NBK + STILE - 1) / STILE);  // ~561

    float* out = (float*)d_out;
    const int* rows = edge_index;
    const int* cols = edge_index + E2;

    // ---- workspace layout (fast path) ----
    float*    ws       = (float*)d_ws;
    float*    dinvAll  = ws;                                   // 2*nent
    float*    sums     = dinvAll + (size_t)2 * nent;           // D
    float*    sumsq    = sums + D;                             // D
    unsigned* cnt      = (unsigned*)(sumsq + D);               // NBK+1 (scan in place)
    unsigned* tsum     = cnt + NBK + 1;                        // ntiles
    unsigned* toff     = tsum + ntiles;                        // ntiles
    float*    T_all    = (float*)(toff + ntiles);              // 2*nrel*D
    uintptr_t pal = ((uintptr_t)(T_all + (size_t)2 * nrel * D) + 15) & ~(uintptr_t)15;
    uint2*    payload  = (uint2*)pal;                          // E2
    size_t needed = (pal + (size_t)E2 * sizeof(uint2)) - (uintptr_t)d_ws;

    bool fast = (needed <= ws_size) && (K <= MAXK) && (2 * nrel <= 1024) &&
                (ntiles <= 1024);

    if (fast) {
        hipMemsetAsync(sums, 0, (size_t)2 * D * sizeof(float), stream);

        transform2_kernel<<<2 * nrel, D, 0, stream>>>(rel_embed_in, w_in, rel_embed_out, w_out,
                                                      T_all, nrel);
        hist4_kernel<<<NB, 512, 0, stream>>>(rows, E2, cnt, NB, K);
        tile_sum_u32<<<ntiles, 256, 0, stream>>>(cnt, tsum, (int)NBK);
        scan_tiles_kernel<<<1, 1024, 0, stream>>>(tsum, toff, cnt, ntiles, (int)NBK);
        base_write_u32<<<ntiles, 256, 0, stream>>>(cnt, toff, cnt, (int)NBK);
        scatter4_kernel<<<NB, 512, 0, stream>>>(rows, cols, edge_type, cnt,
                                                payload, E, E2, nrel, NB, K);
        degsort_kernel<<<K, 512, 0, stream>>>(cnt, payload, dinvAll, nent, nrel, NB, K);
        accum4_kernel<<<K, 512, 0, stream>>>(cnt, payload, T_all, dinvAll,
                                             out, sums, sumsq, nent, nrel, NB, K);
        bn_apply_kernel<<<4096, 256, 0, stream>>>(out, sums, sumsq, bn_gamma, bn_beta, nent);
    } else {
        // ---------- fallback atomic path ----------
        float* f_deg_in  = ws;
        float* f_deg_out = f_deg_in + nent;
        float* f_T_in    = f_deg_out + nent;
        float* f_T_out   = f_T_in + (size_t)nrel * D;
        float* f_sums    = f_T_out + (size_t)nrel * D;
        float* f_sumsq   = f_sums + D;

        hipMemsetAsync(out, 0, (size_t)nent * D * sizeof(float), stream);
        hipMemsetAsync(f_deg_in, 0, (size_t)2 * nent * sizeof(float), stream);
        hipMemsetAsync(f_sums, 0, (size_t)2 * D * sizeof(float), stream);

        transform2_kernel<<<2 * nrel, D, 0, stream>>>(rel_embed_in, w_in, rel_embed_out, w_out,
                                                      f_T_in, nrel);
        degree_kernel<<<1466, 256, 0, stream>>>(edge_index, E, f_deg_in, f_deg_out);
        scatter_kernel<<<2048, 256, 0, stream>>>(rows, cols, edge_type, f_deg_in, f_deg_out,
                                                 f_T_in, f_T_out, out, E);
        bn_stats_kernel<<<1024, D, 0, stream>>>(out, nent, f_sums, f_sumsq);
        bn_apply_kernel<<<4096, 256, 0, stream>>>(out, f_sums, f_sumsq, bn_gamma, bn_beta, nent);
    }

    hipMemcpyAsync(out + (size_t)nent * D, rel_embed,
                   (size_t)nrel * D * sizeof(float), hipMemcpyDeviceToDevice, stream);
}

// Round 10
// 301.840 us; speedup vs baseline: 1.0025x; 1.0025x over previous
//
#include <hip/hip_runtime.h>

#define D 128
#define BUNROLL 8
#define RPB 128                 // rows per bucket
#define CAP 2560                // max edges sorted in LDS per bucket (avg ~1920)
#define MAXK 2048               // max buckets (LDS histogram size)
#define CHUNK4 8192             // edges per block in hist4/scatter4 (identical mapping!)
#define STILE 1024              // scan tile

// ---------------- relation transform (both matrices in one launch) ----------------
__global__ void transform2_kernel(const float* __restrict__ Rin, const float* __restrict__ Win,
                                  const float* __restrict__ Rout, const float* __restrict__ Wout,
                                  float* __restrict__ T_all, int nrel) {
    __shared__ float row[D];
    int b = blockIdx.x;
    bool second = (b >= nrel);
    const float* R = second ? Rout : Rin;
    const float* W = second ? Wout : Win;
    int r = second ? b - nrel : b;
    int t = threadIdx.x;
    row[t] = R[r * D + t];
    __syncthreads();
    float acc = 0.f;
#pragma unroll 8
    for (int k = 0; k < D; ++k) acc += row[k] * W[k * D + t];
    T_all[(size_t)b * D + t] = acc;
}

// ---------------- pass 1: per-block LDS bucket histogram (NO global atomics) ----------------
__global__ __launch_bounds__(512) void hist4_kernel(
        const int* __restrict__ rows, int E2,
        unsigned* __restrict__ cnt, int NB, int K) {
    __shared__ unsigned h[MAXK];
    int tid = threadIdx.x, blk = blockIdx.x;
    for (int i = tid; i < K; i += 512) h[i] = 0;
    __syncthreads();
    long s = (long)blk * CHUNK4;
    long e = s + CHUNK4; if (e > E2) e = E2;
    for (long i = s + tid; i < e; i += 512)
        atomicAdd(&h[((unsigned)rows[i]) >> 7], 1u);
    __syncthreads();
    for (int i = tid; i < K; i += 512)
        cnt[(size_t)i * NB + blk] = h[i];
}

// ---------------- device-wide scan over n=NB*K counters ----------------
__global__ __launch_bounds__(256) void tile_sum_u32(const unsigned int* __restrict__ cnt,
                                                    unsigned int* __restrict__ tsum, int n) {
    int tid = threadIdx.x;
    int i0 = blockIdx.x * STILE + tid * 4;
    unsigned int s = 0;
#pragma unroll
    for (int k = 0; k < 4; ++k) {
        int i = i0 + k;
        if (i < n) s += cnt[i];
    }
    __shared__ unsigned int ls[256];
    ls[tid] = s;
    __syncthreads();
    for (int off = 128; off >= 1; off >>= 1) {
        if (tid < off) ls[tid] += ls[tid + off];
        __syncthreads();
    }
    if (tid == 0) tsum[blockIdx.x] = ls[0];
}

__global__ void scan_tiles_kernel(const unsigned int* __restrict__ tile_sums,
                                  unsigned int* __restrict__ tile_off,
                                  unsigned int* __restrict__ base, int ntiles, int n) {
    int t = threadIdx.x; // blockDim = 1024
    __shared__ unsigned int ls[1024];
    unsigned int v = (t < ntiles) ? tile_sums[t] : 0u;
    ls[t] = v;
    __syncthreads();
    for (int off = 1; off < 1024; off <<= 1) {
        unsigned int add = (t >= off) ? ls[t - off] : 0u;
        __syncthreads();
        ls[t] += add;
        __syncthreads();
    }
    if (t < ntiles) tile_off[t] = ls[t] - v; // exclusive
    if (t == 1023) base[n] = ls[1023];       // grand total
}

// in-place safe when base==cnt
__global__ __launch_bounds__(256) void base_write_u32(const unsigned int* __restrict__ cnt,
                                                      const unsigned int* __restrict__ tile_off,
                                                      unsigned int* __restrict__ base, int n) {
    int tid = threadIdx.x;
    int i0 = blockIdx.x * STILE + tid * 4;
    unsigned int c[4];
#pragma unroll
    for (int k = 0; k < 4; ++k) {
        int i = i0 + k;
        c[k] = (i < n) ? cnt[i] : 0u;
    }
    unsigned int s = c[0] + c[1] + c[2] + c[3];
    __shared__ unsigned int ls[256];
    ls[tid] = s;
    __syncthreads();
    for (int off = 1; off < 256; off <<= 1) {
        unsigned int add = (tid >= off) ? ls[tid - off] : 0u;
        __syncthreads();
        ls[tid] += add;
        __syncthreads();
    }
    unsigned int run = (tid > 0 ? ls[tid - 1] : 0u) + tile_off[blockIdx.x];
#pragma unroll
    for (int k = 0; k < 4; ++k) {
        int i = i0 + k;
        if (i < n) base[i] = run;
        run += c[k];
    }
}

// ---------------- pass 2: scatter with LDS ranks (NO global atomics) ----------------
// payload = (col, (row&127)<<10 | type)
__global__ __launch_bounds__(512) void scatter4_kernel(
        const int* __restrict__ rows, const int* __restrict__ cols,
        const int* __restrict__ etype, const unsigned* __restrict__ base,
        uint2* __restrict__ payload, int E, int E2, int nrel, int NB, int K) {
    __shared__ unsigned cur[MAXK];
    int tid = threadIdx.x, blk = blockIdx.x;
    for (int i = tid; i < K; i += 512) cur[i] = base[(size_t)i * NB + blk];
    __syncthreads();
    long s = (long)blk * CHUNK4;
    long e = s + CHUNK4; if (e > E2) e = E2;
    for (long i = s + tid; i < e; i += 512) {
        unsigned r = (unsigned)rows[i];
        unsigned c = (unsigned)cols[i];
        unsigned t = (unsigned)etype[i];
        unsigned ty = t + ((i < E) ? 0u : (unsigned)nrel);
        unsigned pos = atomicAdd(&cur[r >> 7], 1u);   // LDS atomic
        payload[pos] = make_uint2(c, ((r & 127u) << 10) | ty);
    }
}

// ---------------- degrees + per-bucket row offsets from sorted payload ----------------
// dinvAll[0..nent) = deg_in^-1/2 ; dinvAll[nent..2nent) = deg_out^-1/2
// rowBase[b*128 + r] = exclusive offset of row r's segment within bucket b
__global__ __launch_bounds__(512) void degsort_kernel(
        const unsigned* __restrict__ base, const uint2* __restrict__ payload,
        float* __restrict__ dinvAll, unsigned* __restrict__ rowBase,
        int nent, int nrel, int NB, int K) {
    __shared__ unsigned h2[RPB * 2];
    __shared__ unsigned sc[RPB];
    int tid = threadIdx.x, b = blockIdx.x;
    for (int i = tid; i < RPB * 2; i += 512) h2[i] = 0;
    __syncthreads();
    size_t NBK = (size_t)NB * K;
    unsigned s = base[(size_t)b * NB];
    unsigned e = (b + 1 < K) ? base[(size_t)(b + 1) * NB] : base[NBK];
    for (unsigned i = s + tid; i < e; i += 512) {
        unsigned y = payload[i].y;
        unsigned lr = (y >> 10) & 127u;
        unsigned fo = ((y & 1023u) >= (unsigned)nrel) ? 1u : 0u;
        atomicAdd(&h2[lr * 2 + fo], 1u);
    }
    __syncthreads();
    unsigned tot = 0;
    if (tid < RPB) { tot = h2[tid * 2] + h2[tid * 2 + 1]; sc[tid] = tot; }
    __syncthreads();
    for (int off = 1; off < RPB; off <<= 1) {
        unsigned v = 0;
        if (tid < RPB && tid >= off) v = sc[tid - off];
        __syncthreads();
        if (tid < RPB) sc[tid] += v;
        __syncthreads();
    }
    if (tid < RPB) {
        rowBase[(size_t)b * RPB + tid] = sc[tid] - tot;   // exclusive prefix
        int row = (b << 7) + tid;
        if (row < nent) {
            unsigned a = h2[tid * 2], o = h2[tid * 2 + 1];
            dinvAll[row]        = a ? rsqrtf((float)a) : 0.f;
            dinvAll[nent + row] = o ? rsqrtf((float)o) : 0.f;
        }
    }
}

// ---------------- per-bucket reorder + register accumulate + fused BN stats ----------------
__global__ __launch_bounds__(512) void accum4_kernel(
        const unsigned* __restrict__ base, const uint2* __restrict__ payload,
        const float* __restrict__ T_all, const float* __restrict__ dinvAll,
        const unsigned* __restrict__ rowBase,
        float* __restrict__ out, float* __restrict__ sums, float* __restrict__ sumsq,
        int nent, int nrel, int NB, int K) {
    __shared__ uint2 sp[CAP];              // 20 KB
    __shared__ unsigned hstart[RPB];       // exclusive segment starts
    __shared__ unsigned hcur[RPB];
    __shared__ float ls[D], lq[D];
    int tid = threadIdx.x;
    int b = blockIdx.x;
    size_t NBK = (size_t)NB * K;
    unsigned start = base[(size_t)b * NB];
    unsigned end   = (b + 1 < K) ? base[(size_t)(b + 1) * NB] : base[NBK];
    int n = (int)(end - start);
    int nin = n < CAP ? n : CAP;

    if (tid < RPB) { ls[tid] = 0.f; lq[tid] = 0.f; }

    if (n <= CAP) {
        // fast path: segment offsets precomputed by degsort — single payload pass
        if (tid < RPB) {
            unsigned v = rowBase[(size_t)b * RPB + tid];
            hstart[tid] = v;
            hcur[tid] = v;
        }
        __syncthreads();
        for (int i = tid; i < nin; i += 512) {
            uint2 p = payload[start + i];
            unsigned pos = atomicAdd(&hcur[(p.y >> 10) & 127u], 1u);
            sp[pos] = p;
        }
        __syncthreads();
    } else {
        // overflow fallback: in-kernel truncated histogram + scan + reorder
        if (tid < RPB) hstart[tid] = 0;
        __syncthreads();
        for (int i = tid; i < nin; i += 512)
            atomicAdd(&hstart[(payload[start + i].y >> 10) & 127u], 1u);
        __syncthreads();
        for (int off = 1; off < RPB; off <<= 1) {
            unsigned v = 0;
            if (tid < RPB && tid >= off) v = hstart[tid - off];
            __syncthreads();
            if (tid < RPB) hstart[tid] += v;
            __syncthreads();
        }
        // convert inclusive -> exclusive
        unsigned ex = 0;
        if (tid < RPB) ex = tid ? hstart[tid - 1] : 0u;
        __syncthreads();
        if (tid < RPB) { hstart[tid] = ex; hcur[tid] = ex; }
        __syncthreads();
        for (int i = tid; i < nin; i += 512) {
            uint2 p = payload[start + i];
            unsigned pos = atomicAdd(&hcur[(p.y >> 10) & 127u], 1u);
            sp[pos] = p;
        }
        __syncthreads();
    }

    const float4* T4 = (const float4*)T_all;
    float4* out4 = (float4*)out;
    int hw = tid >> 5, l32 = tid & 31;
    int row0 = b << 7;
    unsigned unrel = (unsigned)nrel;
    float4 s4 = make_float4(0.f, 0.f, 0.f, 0.f);
    float4 q4 = make_float4(0.f, 0.f, 0.f, 0.f);
    for (int rr = 0; rr < 8; ++rr) {
        int r = (hw << 3) + rr;
        int row = row0 + r;
        float da_in = 0.f, da_out = 0.f;
        if (row < nent) { da_in = dinvAll[row]; da_out = dinvAll[nent + row]; }
        unsigned s0 = hstart[r];
        unsigned s1 = (r < RPB - 1) ? hstart[r + 1] : (unsigned)nin;
        float4 a = make_float4(0.f, 0.f, 0.f, 0.f);
        unsigned i = s0;
        for (; i + 4 <= s1; i += 4) {      // 4-deep independent chains
            uint2 p0 = sp[i], p1 = sp[i + 1], p2 = sp[i + 2], p3 = sp[i + 3];
            unsigned ty0 = p0.y & 1023u, ty1 = p1.y & 1023u;
            unsigned ty2 = p2.y & 1023u, ty3 = p3.y & 1023u;
            bool f0 = ty0 < unrel, f1 = ty1 < unrel, f2 = ty2 < unrel, f3 = ty3 < unrel;
            float dc0 = dinvAll[(f0 ? 0 : nent) + p0.x];
            float dc1 = dinvAll[(f1 ? 0 : nent) + p1.x];
            float dc2 = dinvAll[(f2 ? 0 : nent) + p2.x];
            float dc3 = dinvAll[(f3 ? 0 : nent) + p3.x];
            float4 t0 = T4[(size_t)ty0 * 32 + l32];
            float4 t1 = T4[(size_t)ty1 * 32 + l32];
            float4 t2 = T4[(size_t)ty2 * 32 + l32];
            float4 t3 = T4[(size_t)ty3 * 32 + l32];
            float c0 = 0.5f * (f0 ? da_in : da_out) * dc0;
            float c1 = 0.5f * (f1 ? da_in : da_out) * dc1;
            float c2 = 0.5f * (f2 ? da_in : da_out) * dc2;
            float c3 = 0.5f * (f3 ? da_in : da_out) * dc3;
            a.x += c0 * t0.x; a.y += c0 * t0.y; a.z += c0 * t0.z; a.w += c0 * t0.w;
            a.x += c1 * t1.x; a.y += c1 * t1.y; a.z += c1 * t1.z; a.w += c1 * t1.w;
            a.x += c2 * t2.x; a.y += c2 * t2.y; a.z += c2 * t2.z; a.w += c2 * t2.w;
            a.x += c3 * t3.x; a.y += c3 * t3.y; a.z += c3 * t3.z; a.w += c3 * t3.w;
        }
        for (; i < s1; ++i) {
            uint2 p = sp[i];
            unsigned ty = p.y & 1023u;
            bool f = ty < unrel;
            float c = 0.5f * (f ? da_in : da_out) * dinvAll[(f ? 0 : nent) + p.x];
            float4 t = T4[(size_t)ty * 32 + l32];
            a.x += c * t.x; a.y += c * t.y; a.z += c * t.z; a.w += c * t.w;
        }
        // overflow tail (n > CAP): scan remaining global payload (correctness fallback)
        for (unsigned j = start + (unsigned)nin; j < end; ++j) {
            uint2 p = payload[j];
            if (((p.y >> 10) & 127u) == (unsigned)r) {
                unsigned ty = p.y & 1023u;
                bool f = ty < unrel;
                float c = 0.5f * (f ? da_in : da_out) * dinvAll[(f ? 0 : nent) + p.x];
                float4 t = T4[(size_t)ty * 32 + l32];
                a.x += c * t.x; a.y += c * t.y; a.z += c * t.z; a.w += c * t.w;
            }
        }
        if (row < nent) {
            out4[(size_t)row * 32 + l32] = a;
            s4.x += a.x; s4.y += a.y; s4.z += a.z; s4.w += a.w;
            q4.x += a.x * a.x; q4.y += a.y * a.y; q4.z += a.z * a.z; q4.w += a.w * a.w;
        }
    }
    atomicAdd(&ls[4 * l32 + 0], s4.x); atomicAdd(&ls[4 * l32 + 1], s4.y);
    atomicAdd(&ls[4 * l32 + 2], s4.z); atomicAdd(&ls[4 * l32 + 3], s4.w);
    atomicAdd(&lq[4 * l32 + 0], q4.x); atomicAdd(&lq[4 * l32 + 1], q4.y);
    atomicAdd(&lq[4 * l32 + 2], q4.z); atomicAdd(&lq[4 * l32 + 3], q4.w);
    __syncthreads();
    if (tid < D) {
        atomicAdd(&sums[tid], ls[tid]);
        atomicAdd(&sumsq[tid], lq[tid]);
    }
}

// ---------------- fallback (atomic) path kernels ----------------
__global__ __launch_bounds__(256) void degree_kernel(const int* __restrict__ rows, int E,
                                                     float* __restrict__ deg_in,
                                                     float* __restrict__ deg_out) {
    int total = 2 * E;
    int tid = blockIdx.x * blockDim.x + threadIdx.x;
    int nth = gridDim.x * blockDim.x;
    for (long b = (long)tid * BUNROLL; b < total; b += (long)nth * BUNROLL) {
        for (int k = 0; k < BUNROLL && b + k < total; ++k) {
            int r = rows[b + k];
            float* deg = (b + k < E) ? deg_in : deg_out;
            atomicAdd(&deg[r], 1.0f);
        }
    }
}

__global__ void scatter_kernel(const int* __restrict__ rows, const int* __restrict__ cols,
                               const int* __restrict__ etype,
                               const float* __restrict__ deg_in, const float* __restrict__ deg_out,
                               const float* __restrict__ T_in, const float* __restrict__ T_out,
                               float* __restrict__ out, int E) {
    int wave = (blockIdx.x * blockDim.x + threadIdx.x) >> 6;
    int lane = threadIdx.x & 63;
    int nwaves = (gridDim.x * blockDim.x) >> 6;
    int total = 2 * E;
    for (int e = wave; e < total; e += nwaves) {
        bool first = (e < E);
        int row = rows[e];
        int col = cols[e];
        int t = etype[e];
        const float* deg = first ? deg_in : deg_out;
        const float* T = first ? T_in : T_out;
        float dr = deg[row];
        float dc = deg[col];
        float norm = (dr > 0.f ? rsqrtf(dr) : 0.f) * (dc > 0.f ? rsqrtf(dc) : 0.f);
        float c = 0.5f * norm;
        if (c != 0.f) {
            float v0 = c * T[t * D + lane];
            float v1 = c * T[t * D + 64 + lane];
            long b = (long)row * D;
            atomicAdd(&out[b + lane], v0);
            atomicAdd(&out[b + 64 + lane], v1);
        }
    }
}

__global__ void bn_stats_kernel(const float* __restrict__ h, int nent,
                                float* __restrict__ sums, float* __restrict__ sumsq) {
    int col = threadIdx.x;
    float s = 0.f, s2 = 0.f;
    for (int r = blockIdx.x; r < nent; r += gridDim.x) {
        float v = h[(long)r * D + col];
        s += v;
        s2 += v * v;
    }
    atomicAdd(&sums[col], s);
    atomicAdd(&sumsq[col], s2);
}

// ---------------- BN apply (both paths) ----------------
__global__ void bn_apply_kernel(float* __restrict__ h,
                                const float* __restrict__ sums, const float* __restrict__ sumsq,
                                const float* __restrict__ gamma, const float* __restrict__ beta,
                                int nent) {
    long total = ((long)nent * D) / 4;
    long stride = (long)gridDim.x * blockDim.x;
    float inv_n = 1.0f / (float)nent;
    float4* h4 = (float4*)h;
    for (long i = (long)blockIdx.x * blockDim.x + threadIdx.x; i < total; i += stride) {
        int c0 = (int)((i * 4) & (D - 1));
        float4 v = h4[i];
        float r[4] = {v.x, v.y, v.z, v.w};
#pragma unroll
        for (int j = 0; j < 4; ++j) {
            int col = c0 + j;
            float mean = sums[col] * inv_n;
            float var = sumsq[col] * inv_n - mean * mean;
            float istd = rsqrtf(var + 1e-5f);
            r[j] = tanhf((r[j] - mean) * istd * gamma[col] + beta[col]);
        }
        h4[i] = make_float4(r[0], r[1], r[2], r[3]);
    }
}

extern "C" void kernel_launch(void* const* d_in, const int* in_sizes, int n_in,
                              void* d_out, int out_size, void* d_ws, size_t ws_size,
                              hipStream_t stream) {
    const float* rel_embed     = (const float*)d_in[0];
    const float* rel_embed_in  = (const float*)d_in[1];
    const float* rel_embed_out = (const float*)d_in[2];
    const float* w_in          = (const float*)d_in[3];
    const float* w_out         = (const float*)d_in[4];
    const float* bn_gamma      = (const float*)d_in[5];
    const float* bn_beta       = (const float*)d_in[6];
    const int*   edge_index    = (const int*)d_in[7];
    const int*   edge_type     = (const int*)d_in[8];

    const int nrel = in_sizes[0] / D;               // 500
    const int E2   = in_sizes[8];                   // 3,000,000
    const int E    = E2 / 2;                        // 1,500,000
    const int nent = (out_size - in_sizes[0]) / D;  // 200,000
    const int K    = (nent + RPB - 1) / RPB;        // 1563 buckets
    const int NB   = (E2 + CHUNK4 - 1) / CHUNK4;    // 367 blocks
    const long NBK = (long)NB * K;                  // ~574K counters
    const int ntiles = (int)((NBK + STILE - 1) / STILE);  // ~561

    float* out = (float*)d_out;
    const int* rows = edge_index;
    const int* cols = edge_index + E2;

    // ---- workspace layout (fast path) ----
    float*    ws       = (float*)d_ws;
    float*    dinvAll  = ws;                                   // 2*nent
    float*    sums     = dinvAll + (size_t)2 * nent;           // D
    float*    sumsq    = sums + D;                             // D
    unsigned* rowBase  = (unsigned*)(sumsq + D);               // K*RPB
    unsigned* cnt      = rowBase + (size_t)K * RPB;            // NBK+1 (scan in place)
    unsigned* tsum     = cnt + NBK + 1;                        // ntiles
    unsigned* toff     = tsum + ntiles;                        // ntiles
    float*    T_all    = (float*)(toff + ntiles);              // 2*nrel*D
    uintptr_t pal = ((uintptr_t)(T_all + (size_t)2 * nrel * D) + 15) & ~(uintptr_t)15;
    uint2*    payload  = (uint2*)pal;                          // E2
    size_t needed = (pal + (size_t)E2 * sizeof(uint2)) - (uintptr_t)d_ws;

    bool fast = (needed <= ws_size) && (K <= MAXK) && (2 * nrel <= 1024) &&
                (ntiles <= 1024);

    if (fast) {
        hipMemsetAsync(sums, 0, (size_t)2 * D * sizeof(float), stream);

        transform2_kernel<<<2 * nrel, D, 0, stream>>>(rel_embed_in, w_in, rel_embed_out, w_out,
                                                      T_all, nrel);
        hist4_kernel<<<NB, 512, 0, stream>>>(rows, E2, cnt, NB, K);
        tile_sum_u32<<<ntiles, 256, 0, stream>>>(cnt, tsum, (int)NBK);
        scan_tiles_kernel<<<1, 1024, 0, stream>>>(tsum, toff, cnt, ntiles, (int)NBK);
        base_write_u32<<<ntiles, 256, 0, stream>>>(cnt, toff, cnt, (int)NBK);
        scatter4_kernel<<<NB, 512, 0, stream>>>(rows, cols, edge_type, cnt,
                                                payload, E, E2, nrel, NB, K);
        degsort_kernel<<<K, 512, 0, stream>>>(cnt, payload, dinvAll, rowBase,
                                              nent, nrel, NB, K);
        accum4_kernel<<<K, 512, 0, stream>>>(cnt, payload, T_all, dinvAll, rowBase,
                                             out, sums, sumsq, nent, nrel, NB, K);
        bn_apply_kernel<<<4096, 256, 0, stream>>>(out, sums, sumsq, bn_gamma, bn_beta, nent);
    } else {
        // ---------- fallback atomic path ----------
        float* f_deg_in  = ws;
        float* f_deg_out = f_deg_in + nent;
        float* f_T_in    = f_deg_out + nent;
        float* f_T_out   = f_T_in + (size_t)nrel * D;
        float* f_sums    = f_T_out + (size_t)nrel * D;
        float* f_sumsq   = f_sums + D;

        hipMemsetAsync(out, 0, (size_t)nent * D * sizeof(float), stream);
        hipMemsetAsync(f_deg_in, 0, (size_t)2 * nent * sizeof(float), stream);
        hipMemsetAsync(f_sums, 0, (size_t)2 * D * sizeof(float), stream);

        transform2_kernel<<<2 * nrel, D, 0, stream>>>(rel_embed_in, w_in, rel_embed_out, w_out,
                                                      f_T_in, nrel);
        degree_kernel<<<1466, 256, 0, stream>>>(edge_index, E, f_deg_in, f_deg_out);
        scatter_kernel<<<2048, 256, 0, stream>>>(rows, cols, edge_type, f_deg_in, f_deg_out,
                                                 f_T_in, f_T_out, out, E);
        bn_stats_kernel<<<1024, D, 0, stream>>>(out, nent, f_sums, f_sumsq);
        bn_apply_kernel<<<4096, 256, 0, stream>>>(out, f_sums, f_sumsq, bn_gamma, bn_beta, nent);
    }

    hipMemcpyAsync(out + (size_t)nent * D, rel_embed,
                   (size_t)nrel * D * sizeof(float), hipMemcpyDeviceToDevice, stream);
}

// Round 11
// 296.971 us; speedup vs baseline: 1.0189x; 1.0164x over previous
//
#include <hip/hip_runtime.h>

#define D 128
#define BUNROLL 8
#define RPB 128                 // rows per bucket
#define CAP 2560                // max edges sorted in LDS per bucket (avg ~1920)
#define MAXK 2048               // max buckets (LDS histogram size)
#define CHUNK4 8192             // edges per block in hist4/scatter4 (identical mapping!)
#define STILE 1024              // scan tile

__device__ __forceinline__ unsigned f2bf_rne(float x) {
    unsigned u = __float_as_uint(x);
    return (u + 0x7fffu + ((u >> 16) & 1u)) >> 16;
}

// ---------------- relation transform -> bf16 table (fast path) ----------------
__global__ void transform2_bf_kernel(const float* __restrict__ Rin, const float* __restrict__ Win,
                                     const float* __restrict__ Rout, const float* __restrict__ Wout,
                                     unsigned short* __restrict__ T_bf, int nrel) {
    __shared__ float row[D];
    int b = blockIdx.x;
    bool second = (b >= nrel);
    const float* R = second ? Rout : Rin;
    const float* W = second ? Wout : Win;
    int r = second ? b - nrel : b;
    int t = threadIdx.x;
    row[t] = R[r * D + t];
    __syncthreads();
    float acc = 0.f;
#pragma unroll 8
    for (int k = 0; k < D; ++k) acc += row[k] * W[k * D + t];
    T_bf[(size_t)b * D + t] = (unsigned short)f2bf_rne(acc);
}

// f32 version (fallback path)
__global__ void transform2_kernel(const float* __restrict__ Rin, const float* __restrict__ Win,
                                  const float* __restrict__ Rout, const float* __restrict__ Wout,
                                  float* __restrict__ T_all, int nrel) {
    __shared__ float row[D];
    int b = blockIdx.x;
    bool second = (b >= nrel);
    const float* R = second ? Rout : Rin;
    const float* W = second ? Wout : Win;
    int r = second ? b - nrel : b;
    int t = threadIdx.x;
    row[t] = R[r * D + t];
    __syncthreads();
    float acc = 0.f;
#pragma unroll 8
    for (int k = 0; k < D; ++k) acc += row[k] * W[k * D + t];
    T_all[(size_t)b * D + t] = acc;
}

// ---------------- pass 1: per-block LDS bucket histogram (NO global atomics) ----------------
__global__ __launch_bounds__(512) void hist4_kernel(
        const int* __restrict__ rows, int E2,
        unsigned* __restrict__ cnt, int NB, int K) {
    __shared__ unsigned h[MAXK];
    int tid = threadIdx.x, blk = blockIdx.x;
    for (int i = tid; i < K; i += 512) h[i] = 0;
    __syncthreads();
    long s = (long)blk * CHUNK4;
    long e = s + CHUNK4; if (e > E2) e = E2;
    for (long i = s + tid; i < e; i += 512)
        atomicAdd(&h[((unsigned)rows[i]) >> 7], 1u);
    __syncthreads();
    for (int i = tid; i < K; i += 512)
        cnt[(size_t)i * NB + blk] = h[i];
}

// ---------------- device-wide scan over n=NB*K counters ----------------
__global__ __launch_bounds__(256) void tile_sum_u32(const unsigned int* __restrict__ cnt,
                                                    unsigned int* __restrict__ tsum, int n) {
    int tid = threadIdx.x;
    int i0 = blockIdx.x * STILE + tid * 4;
    unsigned int s = 0;
#pragma unroll
    for (int k = 0; k < 4; ++k) {
        int i = i0 + k;
        if (i < n) s += cnt[i];
    }
    __shared__ unsigned int ls[256];
    ls[tid] = s;
    __syncthreads();
    for (int off = 128; off >= 1; off >>= 1) {
        if (tid < off) ls[tid] += ls[tid + off];
        __syncthreads();
    }
    if (tid == 0) tsum[blockIdx.x] = ls[0];
}

__global__ void scan_tiles_kernel(const unsigned int* __restrict__ tile_sums,
                                  unsigned int* __restrict__ tile_off,
                                  unsigned int* __restrict__ base, int ntiles, int n) {
    int t = threadIdx.x; // blockDim = 1024
    __shared__ unsigned int ls[1024];
    unsigned int v = (t < ntiles) ? tile_sums[t] : 0u;
    ls[t] = v;
    __syncthreads();
    for (int off = 1; off < 1024; off <<= 1) {
        unsigned int add = (t >= off) ? ls[t - off] : 0u;
        __syncthreads();
        ls[t] += add;
        __syncthreads();
    }
    if (t < ntiles) tile_off[t] = ls[t] - v; // exclusive
    if (t == 1023) base[n] = ls[1023];       // grand total
}

// in-place safe when base==cnt
__global__ __launch_bounds__(256) void base_write_u32(const unsigned int* __restrict__ cnt,
                                                      const unsigned int* __restrict__ tile_off,
                                                      unsigned int* __restrict__ base, int n) {
    int tid = threadIdx.x;
    int i0 = blockIdx.x * STILE + tid * 4;
    unsigned int c[4];
#pragma unroll
    for (int k = 0; k < 4; ++k) {
        int i = i0 + k;
        c[k] = (i < n) ? cnt[i] : 0u;
    }
    unsigned int s = c[0] + c[1] + c[2] + c[3];
    __shared__ unsigned int ls[256];
    ls[tid] = s;
    __syncthreads();
    for (int off = 1; off < 256; off <<= 1) {
        unsigned int add = (tid >= off) ? ls[tid - off] : 0u;
        __syncthreads();
        ls[tid] += add;
        __syncthreads();
    }
    unsigned int run = (tid > 0 ? ls[tid - 1] : 0u) + tile_off[blockIdx.x];
#pragma unroll
    for (int k = 0; k < 4; ++k) {
        int i = i0 + k;
        if (i < n) base[i] = run;
        run += c[k];
    }
}

// ---------------- pass 2: scatter with LDS ranks (NO global atomics) ----------------
// payload = (col, (row&127)<<10 | type)
__global__ __launch_bounds__(512) void scatter4_kernel(
        const int* __restrict__ rows, const int* __restrict__ cols,
        const int* __restrict__ etype, const unsigned* __restrict__ base,
        uint2* __restrict__ payload, int E, int E2, int nrel, int NB, int K) {
    __shared__ unsigned cur[MAXK];
    int tid = threadIdx.x, blk = blockIdx.x;
    for (int i = tid; i < K; i += 512) cur[i] = base[(size_t)i * NB + blk];
    __syncthreads();
    long s = (long)blk * CHUNK4;
    long e = s + CHUNK4; if (e > E2) e = E2;
    for (long i = s + tid; i < e; i += 512) {
        unsigned r = (unsigned)rows[i];
        unsigned c = (unsigned)cols[i];
        unsigned t = (unsigned)etype[i];
        unsigned ty = t + ((i < E) ? 0u : (unsigned)nrel);
        unsigned pos = atomicAdd(&cur[r >> 7], 1u);   // LDS atomic
        payload[pos] = make_uint2(c, ((r & 127u) << 10) | ty);
    }
}

// ---------------- degrees + per-bucket row offsets from sorted payload ----------------
__global__ __launch_bounds__(512) void degsort_kernel(
        const unsigned* __restrict__ base, const uint2* __restrict__ payload,
        float* __restrict__ dinvAll, unsigned* __restrict__ rowBase,
        int nent, int nrel, int NB, int K) {
    __shared__ unsigned h2[RPB * 2];
    __shared__ unsigned sc[RPB];
    int tid = threadIdx.x, b = blockIdx.x;
    for (int i = tid; i < RPB * 2; i += 512) h2[i] = 0;
    __syncthreads();
    size_t NBK = (size_t)NB * K;
    unsigned s = base[(size_t)b * NB];
    unsigned e = (b + 1 < K) ? base[(size_t)(b + 1) * NB] : base[NBK];
    for (unsigned i = s + tid; i < e; i += 512) {
        unsigned y = payload[i].y;
        unsigned lr = (y >> 10) & 127u;
        unsigned fo = ((y & 1023u) >= (unsigned)nrel) ? 1u : 0u;
        atomicAdd(&h2[lr * 2 + fo], 1u);
    }
    __syncthreads();
    unsigned tot = 0;
    if (tid < RPB) { tot = h2[tid * 2] + h2[tid * 2 + 1]; sc[tid] = tot; }
    __syncthreads();
    for (int off = 1; off < RPB; off <<= 1) {
        unsigned v = 0;
        if (tid < RPB && tid >= off) v = sc[tid - off];
        __syncthreads();
        if (tid < RPB) sc[tid] += v;
        __syncthreads();
    }
    if (tid < RPB) {
        rowBase[(size_t)b * RPB + tid] = sc[tid] - tot;   // exclusive prefix
        int row = (b << 7) + tid;
        if (row < nent) {
            unsigned a = h2[tid * 2], o = h2[tid * 2 + 1];
            dinvAll[row]        = a ? rsqrtf((float)a) : 0.f;
            dinvAll[nent + row] = o ? rsqrtf((float)o) : 0.f;
        }
    }
}

// ---------------- per-bucket reorder + register accumulate (bf16 T) + fused BN stats ----------------
__global__ __launch_bounds__(512) void accum4_kernel(
        const unsigned* __restrict__ base, const uint2* __restrict__ payload,
        const unsigned short* __restrict__ T_bf, const float* __restrict__ dinvAll,
        const unsigned* __restrict__ rowBase,
        float* __restrict__ out, float* __restrict__ sums, float* __restrict__ sumsq,
        int nent, int nrel, int NB, int K) {
    __shared__ uint2 sp[CAP];              // 20 KB
    __shared__ unsigned hstart[RPB];
    __shared__ unsigned hcur[RPB];
    __shared__ float ls[D], lq[D];
    int tid = threadIdx.x;
    int b = blockIdx.x;
    size_t NBK = (size_t)NB * K;
    unsigned start = base[(size_t)b * NB];
    unsigned end   = (b + 1 < K) ? base[(size_t)(b + 1) * NB] : base[NBK];
    int n = (int)(end - start);
    int nin = n < CAP ? n : CAP;

    if (tid < RPB) { ls[tid] = 0.f; lq[tid] = 0.f; }

    if (n <= CAP) {
        if (tid < RPB) {
            unsigned v = rowBase[(size_t)b * RPB + tid];
            hstart[tid] = v;
            hcur[tid] = v;
        }
        __syncthreads();
        for (int i = tid; i < nin; i += 512) {
            uint2 p = payload[start + i];
            unsigned pos = atomicAdd(&hcur[(p.y >> 10) & 127u], 1u);
            sp[pos] = p;
        }
        __syncthreads();
    } else {
        if (tid < RPB) hstart[tid] = 0;
        __syncthreads();
        for (int i = tid; i < nin; i += 512)
            atomicAdd(&hstart[(payload[start + i].y >> 10) & 127u], 1u);
        __syncthreads();
        for (int off = 1; off < RPB; off <<= 1) {
            unsigned v = 0;
            if (tid < RPB && tid >= off) v = hstart[tid - off];
            __syncthreads();
            if (tid < RPB) hstart[tid] += v;
            __syncthreads();
        }
        unsigned ex = 0;
        if (tid < RPB) ex = tid ? hstart[tid - 1] : 0u;
        __syncthreads();
        if (tid < RPB) { hstart[tid] = ex; hcur[tid] = ex; }
        __syncthreads();
        for (int i = tid; i < nin; i += 512) {
            uint2 p = payload[start + i];
            unsigned pos = atomicAdd(&hcur[(p.y >> 10) & 127u], 1u);
            sp[pos] = p;
        }
        __syncthreads();
    }

    const uint2* T2 = (const uint2*)T_bf;   // one row = 128 bf16 = 32 uint2
    float4* out4 = (float4*)out;
    int hw = tid >> 5, l32 = tid & 31;
    int row0 = b << 7;
    unsigned unrel = (unsigned)nrel;
    float4 s4 = make_float4(0.f, 0.f, 0.f, 0.f);
    float4 q4 = make_float4(0.f, 0.f, 0.f, 0.f);
    for (int rr = 0; rr < 8; ++rr) {
        int r = (hw << 3) + rr;
        int row = row0 + r;
        float da_in = 0.f, da_out = 0.f;
        if (row < nent) { da_in = dinvAll[row]; da_out = dinvAll[nent + row]; }
        unsigned s0 = hstart[r];
        unsigned s1 = (r < RPB - 1) ? hstart[r + 1] : (unsigned)nin;
        float4 a = make_float4(0.f, 0.f, 0.f, 0.f);
        unsigned i = s0;
        for (; i + 4 <= s1; i += 4) {      // 4-deep independent chains
            uint2 p0 = sp[i], p1 = sp[i + 1], p2 = sp[i + 2], p3 = sp[i + 3];
            unsigned ty0 = p0.y & 1023u, ty1 = p1.y & 1023u;
            unsigned ty2 = p2.y & 1023u, ty3 = p3.y & 1023u;
            bool f0 = ty0 < unrel, f1 = ty1 < unrel, f2 = ty2 < unrel, f3 = ty3 < unrel;
            float dc0 = dinvAll[(f0 ? 0 : nent) + p0.x];
            float dc1 = dinvAll[(f1 ? 0 : nent) + p1.x];
            float dc2 = dinvAll[(f2 ? 0 : nent) + p2.x];
            float dc3 = dinvAll[(f3 ? 0 : nent) + p3.x];
            uint2 t0 = T2[(size_t)ty0 * 32 + l32];
            uint2 t1 = T2[(size_t)ty1 * 32 + l32];
            uint2 t2 = T2[(size_t)ty2 * 32 + l32];
            uint2 t3 = T2[(size_t)ty3 * 32 + l32];
            float c0 = 0.5f * (f0 ? da_in : da_out) * dc0;
            float c1 = 0.5f * (f1 ? da_in : da_out) * dc1;
            float c2 = 0.5f * (f2 ? da_in : da_out) * dc2;
            float c3 = 0.5f * (f3 ? da_in : da_out) * dc3;
            a.x += c0 * __uint_as_float(t0.x << 16);
            a.y += c0 * __uint_as_float(t0.x & 0xffff0000u);
            a.z += c0 * __uint_as_float(t0.y << 16);
            a.w += c0 * __uint_as_float(t0.y & 0xffff0000u);
            a.x += c1 * __uint_as_float(t1.x << 16);
            a.y += c1 * __uint_as_float(t1.x & 0xffff0000u);
            a.z += c1 * __uint_as_float(t1.y << 16);
            a.w += c1 * __uint_as_float(t1.y & 0xffff0000u);
            a.x += c2 * __uint_as_float(t2.x << 16);
            a.y += c2 * __uint_as_float(t2.x & 0xffff0000u);
            a.z += c2 * __uint_as_float(t2.y << 16);
            a.w += c2 * __uint_as_float(t2.y & 0xffff0000u);
            a.x += c3 * __uint_as_float(t3.x << 16);
            a.y += c3 * __uint_as_float(t3.x & 0xffff0000u);
            a.z += c3 * __uint_as_float(t3.y << 16);
            a.w += c3 * __uint_as_float(t3.y & 0xffff0000u);
        }
        for (; i < s1; ++i) {
            uint2 p = sp[i];
            unsigned ty = p.y & 1023u;
            bool f = ty < unrel;
            float c = 0.5f * (f ? da_in : da_out) * dinvAll[(f ? 0 : nent) + p.x];
            uint2 t = T2[(size_t)ty * 32 + l32];
            a.x += c * __uint_as_float(t.x << 16);
            a.y += c * __uint_as_float(t.x & 0xffff0000u);
            a.z += c * __uint_as_float(t.y << 16);
            a.w += c * __uint_as_float(t.y & 0xffff0000u);
        }
        // overflow tail (n > CAP): correctness fallback
        for (unsigned j = start + (unsigned)nin; j < end; ++j) {
            uint2 p = payload[j];
            if (((p.y >> 10) & 127u) == (unsigned)r) {
                unsigned ty = p.y & 1023u;
                bool f = ty < unrel;
                float c = 0.5f * (f ? da_in : da_out) * dinvAll[(f ? 0 : nent) + p.x];
                uint2 t = T2[(size_t)ty * 32 + l32];
                a.x += c * __uint_as_float(t.x << 16);
                a.y += c * __uint_as_float(t.x & 0xffff0000u);
                a.z += c * __uint_as_float(t.y << 16);
                a.w += c * __uint_as_float(t.y & 0xffff0000u);
            }
        }
        if (row < nent) {
            out4[(size_t)row * 32 + l32] = a;
            s4.x += a.x; s4.y += a.y; s4.z += a.z; s4.w += a.w;
            q4.x += a.x * a.x; q4.y += a.y * a.y; q4.z += a.z * a.z; q4.w += a.w * a.w;
        }
    }
    atomicAdd(&ls[4 * l32 + 0], s4.x); atomicAdd(&ls[4 * l32 + 1], s4.y);
    atomicAdd(&ls[4 * l32 + 2], s4.z); atomicAdd(&ls[4 * l32 + 3], s4.w);
    atomicAdd(&lq[4 * l32 + 0], q4.x); atomicAdd(&lq[4 * l32 + 1], q4.y);
    atomicAdd(&lq[4 * l32 + 2], q4.z); atomicAdd(&lq[4 * l32 + 3], q4.w);
    __syncthreads();
    if (tid < D) {
        atomicAdd(&sums[tid], ls[tid]);
        atomicAdd(&sumsq[tid], lq[tid]);
    }
}

// ---------------- fallback (atomic) path kernels ----------------
__global__ __launch_bounds__(256) void degree_kernel(const int* __restrict__ rows, int E,
                                                     float* __restrict__ deg_in,
                                                     float* __restrict__ deg_out) {
    int total = 2 * E;
    int tid = blockIdx.x * blockDim.x + threadIdx.x;
    int nth = gridDim.x * blockDim.x;
    for (long b = (long)tid * BUNROLL; b < total; b += (long)nth * BUNROLL) {
        for (int k = 0; k < BUNROLL && b + k < total; ++k) {
            int r = rows[b + k];
            float* deg = (b + k < E) ? deg_in : deg_out;
            atomicAdd(&deg[r], 1.0f);
        }
    }
}

__global__ void scatter_kernel(const int* __restrict__ rows, const int* __restrict__ cols,
                               const int* __restrict__ etype,
                               const float* __restrict__ deg_in, const float* __restrict__ deg_out,
                               const float* __restrict__ T_in, const float* __restrict__ T_out,
                               float* __restrict__ out, int E) {
    int wave = (blockIdx.x * blockDim.x + threadIdx.x) >> 6;
    int lane = threadIdx.x & 63;
    int nwaves = (gridDim.x * blockDim.x) >> 6;
    int total = 2 * E;
    for (int e = wave; e < total; e += nwaves) {
        bool first = (e < E);
        int row = rows[e];
        int col = cols[e];
        int t = etype[e];
        const float* deg = first ? deg_in : deg_out;
        const float* T = first ? T_in : T_out;
        float dr = deg[row];
        float dc = deg[col];
        float norm = (dr > 0.f ? rsqrtf(dr) : 0.f) * (dc > 0.f ? rsqrtf(dc) : 0.f);
        float c = 0.5f * norm;
        if (c != 0.f) {
            float v0 = c * T[t * D + lane];
            float v1 = c * T[t * D + 64 + lane];
            long b = (long)row * D;
            atomicAdd(&out[b + lane], v0);
            atomicAdd(&out[b + 64 + lane], v1);
        }
    }
}

__global__ void bn_stats_kernel(const float* __restrict__ h, int nent,
                                float* __restrict__ sums, float* __restrict__ sumsq) {
    int col = threadIdx.x;
    float s = 0.f, s2 = 0.f;
    for (int r = blockIdx.x; r < nent; r += gridDim.x) {
        float v = h[(long)r * D + col];
        s += v;
        s2 += v * v;
    }
    atomicAdd(&sums[col], s);
    atomicAdd(&sumsq[col], s2);
}

// ---------------- BN apply (both paths) ----------------
__global__ void bn_apply_kernel(float* __restrict__ h,
                                const float* __restrict__ sums, const float* __restrict__ sumsq,
                                const float* __restrict__ gamma, const float* __restrict__ beta,
                                int nent) {
    long total = ((long)nent * D) / 4;
    long stride = (long)gridDim.x * blockDim.x;
    float inv_n = 1.0f / (float)nent;
    float4* h4 = (float4*)h;
    for (long i = (long)blockIdx.x * blockDim.x + threadIdx.x; i < total; i += stride) {
        int c0 = (int)((i * 4) & (D - 1));
        float4 v = h4[i];
        float r[4] = {v.x, v.y, v.z, v.w};
#pragma unroll
        for (int j = 0; j < 4; ++j) {
            int col = c0 + j;
            float mean = sums[col] * inv_n;
            float var = sumsq[col] * inv_n - mean * mean;
            float istd = rsqrtf(var + 1e-5f);
            r[j] = tanhf((r[j] - mean) * istd * gamma[col] + beta[col]);
        }
        h4[i] = make_float4(r[0], r[1], r[2], r[3]);
    }
}

extern "C" void kernel_launch(void* const* d_in, const int* in_sizes, int n_in,
                              void* d_out, int out_size, void* d_ws, size_t ws_size,
                              hipStream_t stream) {
    const float* rel_embed     = (const float*)d_in[0];
    const float* rel_embed_in  = (const float*)d_in[1];
    const float* rel_embed_out = (const float*)d_in[2];
    const float* w_in          = (const float*)d_in[3];
    const float* w_out         = (const float*)d_in[4];
    const float* bn_gamma      = (const float*)d_in[5];
    const float* bn_beta       = (const float*)d_in[6];
    const int*   edge_index    = (const int*)d_in[7];
    const int*   edge_type     = (const int*)d_in[8];

    const int nrel = in_sizes[0] / D;               // 500
    const int E2   = in_sizes[8];                   // 3,000,000
    const int E    = E2 / 2;                        // 1,500,000
    const int nent = (out_size - in_sizes[0]) / D;  // 200,000
    const int K    = (nent + RPB - 1) / RPB;        // 1563 buckets
    const int NB   = (E2 + CHUNK4 - 1) / CHUNK4;    // 367 blocks
    const long NBK = (long)NB * K;                  // ~574K counters
    const int ntiles = (int)((NBK + STILE - 1) / STILE);  // ~561

    float* out = (float*)d_out;
    const int* rows = edge_index;
    const int* cols = edge_index + E2;

    // ---- workspace layout (fast path) ----
    float*          ws       = (float*)d_ws;
    float*          dinvAll  = ws;                                   // 2*nent
    float*          sums     = dinvAll + (size_t)2 * nent;           // D
    float*          sumsq    = sums + D;                             // D
    unsigned*       rowBase  = (unsigned*)(sumsq + D);               // K*RPB
    unsigned*       cnt      = rowBase + (size_t)K * RPB;            // NBK+1 (scan in place)
    unsigned*       tsum     = cnt + NBK + 1;                        // ntiles
    unsigned*       toff     = tsum + ntiles;                        // ntiles
    unsigned short* T_bf     = (unsigned short*)(toff + ntiles);     // 2*nrel*D bf16
    uintptr_t pal = ((uintptr_t)(T_bf + (size_t)2 * nrel * D) + 15) & ~(uintptr_t)15;
    uint2*          payload  = (uint2*)pal;                          // E2
    size_t needed = (pal + (size_t)E2 * sizeof(uint2)) - (uintptr_t)d_ws;

    bool fast = (needed <= ws_size) && (K <= MAXK) && (2 * nrel <= 1024) &&
                (ntiles <= 1024);

    if (fast) {
        hipMemsetAsync(sums, 0, (size_t)2 * D * sizeof(float), stream);

        transform2_bf_kernel<<<2 * nrel, D, 0, stream>>>(rel_embed_in, w_in,
                                                         rel_embed_out, w_out, T_bf, nrel);
        hist4_kernel<<<NB, 512, 0, stream>>>(rows, E2, cnt, NB, K);
        tile_sum_u32<<<ntiles, 256, 0, stream>>>(cnt, tsum, (int)NBK);
        scan_tiles_kernel<<<1, 1024, 0, stream>>>(tsum, toff, cnt, ntiles, (int)NBK);
        base_write_u32<<<ntiles, 256, 0, stream>>>(cnt, toff, cnt, (int)NBK);
        scatter4_kernel<<<NB, 512, 0, stream>>>(rows, cols, edge_type, cnt,
                                                payload, E, E2, nrel, NB, K);
        degsort_kernel<<<K, 512, 0, stream>>>(cnt, payload, dinvAll, rowBase,
                                              nent, nrel, NB, K);
        accum4_kernel<<<K, 512, 0, stream>>>(cnt, payload, T_bf, dinvAll, rowBase,
                                             out, sums, sumsq, nent, nrel, NB, K);
        bn_apply_kernel<<<4096, 256, 0, stream>>>(out, sums, sumsq, bn_gamma, bn_beta, nent);
    } else {
        // ---------- fallback atomic path (f32 everywhere) ----------
        float* f_deg_in  = ws;
        float* f_deg_out = f_deg_in + nent;
        float* f_T_in    = f_deg_out + nent;
        float* f_T_out   = f_T_in + (size_t)nrel * D;
        float* f_sums    = f_T_out + (size_t)nrel * D;
        float* f_sumsq   = f_sums + D;

        hipMemsetAsync(out, 0, (size_t)nent * D * sizeof(float), stream);
        hipMemsetAsync(f_deg_in, 0, (size_t)2 * nent * sizeof(float), stream);
        hipMemsetAsync(f_sums, 0, (size_t)2 * D * sizeof(float), stream);

        transform2_kernel<<<2 * nrel, D, 0, stream>>>(rel_embed_in, w_in, rel_embed_out, w_out,
                                                      f_T_in, nrel);
        degree_kernel<<<1466, 256, 0, stream>>>(edge_index, E, f_deg_in, f_deg_out);
        scatter_kernel<<<2048, 256, 0, stream>>>(rows, cols, edge_type, f_deg_in, f_deg_out,
                                                 f_T_in, f_T_out, out, E);
        bn_stats_kernel<<<1024, D, 0, stream>>>(out, nent, f_sums, f_sumsq);
        bn_apply_kernel<<<4096, 256, 0, stream>>>(out, f_sums, f_sumsq, bn_gamma, bn_beta, nent);
    }

    hipMemcpyAsync(out + (size_t)nent * D, rel_embed,
                   (size_t)nrel * D * sizeof(float), hipMemcpyDeviceToDevice, stream);
}